// Round 2
// baseline (52966.858 us; speedup 1.0000x reference)
//
#include <hip/hip_runtime.h>

#define NN 1000
#define NP 1024
#define NBLK 16            // cooperating blocks, 64 neurons each
#define RPB 64             // rows (neurons) per block
#define TPB 512            // 8 waves: wave 0 = state+rows, waves 0..7 = column groups
#define ST_FLOATS (NN * NP)            // 1,024,000 floats = 4,096,000 B
#define COMM_OFF  (ST_FLOATS * 4)      // comm area right after ST in d_ws

struct alignas(128) Comm {
    unsigned long long m;   // fired mask for this block's 64 neurons
    unsigned int flag;      // stamp = t+1 when m is valid for step t
    unsigned int pad[29];
};
static_assert(sizeof(Comm) == 128, "Comm must be one 128B line");

// S[NN][NN] row-major -> ST[j][i] (column j contiguous over padded i, stride 1024).
// Only rows j < NN are ever read (padding neurons never fire).
__global__ void transpose_S(const float* __restrict__ S, float* __restrict__ ST) {
    int idx = blockIdx.x * blockDim.x + threadIdx.x;   // 0 .. NN*NP-1 exactly
    int j = idx >> 10;          // 0..999
    int i = idx & (NP - 1);     // 0..1023
    float val = (i < NN) ? S[i * NN + j] : 0.0f;
    ST[(j << 10) + i] = val;
}

__global__ void __launch_bounds__(TPB) izhikevich_sim(
    const float* __restrict__ data, const float* __restrict__ U,
    const float* __restrict__ ST, Comm* __restrict__ comm,
    const float* __restrict__ a, const float* __restrict__ b,
    const float* __restrict__ c, const float* __restrict__ d,
    const float* __restrict__ v0, const float* __restrict__ u0,
    float* __restrict__ out_states, float* __restrict__ out_v,
    float* __restrict__ out_u, float* __restrict__ out_fir, int T)
{
    __shared__ int   cnt[NBLK];          // fired count per 64-neuron word
    __shared__ int   fidx[NBLK * 64];    // fired neuron indices per word
    __shared__ float psum[8 * RPB];      // per-group partial sums

    const int tid = threadIdx.x;
    const int g   = tid >> 6;            // column group 0..7 (wave id)
    const int r   = tid & 63;            // lane / local row
    const int blk = blockIdx.x;
    const int i   = blk * RPB + r;       // global neuron owned by wave-0 lane r
    const bool isw0 = (g == 0);
    const bool act  = isw0 && (i < NN);

    float v = 0.f, u = 0.f, ai = 0.f, bi = 0.f, ci = 0.f, di = 0.f, Ui = 0.f;
    if (act) {
        v = v0[i]; u = u0[i];
        ai = a[i]; bi = b[i]; ci = c[i]; di = d[i]; Ui = U[i];
    }
    bool fired = false;
    const int colbase = (blk << 6) + r;  // row offset within a 1024-stride column

    for (int t = 0; t < T; ++t) {
        if (isw0) {
            // fired mask at start of step t
            fired = act && (v >= 30.0f);
            unsigned long long m = __ballot(fired);
            if (r == 0) {
                Comm* cme = &comm[((t & 1) * NBLK) + blk];
                __hip_atomic_store(&cme->m, m, __ATOMIC_RELAXED, __HIP_MEMORY_SCOPE_AGENT);
                __hip_atomic_store(&cme->flag, (unsigned)(t + 1), __ATOMIC_RELEASE, __HIP_MEMORY_SCOPE_AGENT);
            }
            // reference applies reset twice: v=c (idempotent), u += 2*d
            if (fired) { v = ci; u += 2.0f * di; }

            // 16 lanes poll all 16 blocks' masks (incl. our own) in parallel
            if (r < NBLK) {
                Comm* cw = &comm[((t & 1) * NBLK) + r];
                while (__hip_atomic_load(&cw->flag, __ATOMIC_ACQUIRE,
                                         __HIP_MEMORY_SCOPE_AGENT) < (unsigned)(t + 1)) { }
                unsigned long long mm = __hip_atomic_load(&cw->m, __ATOMIC_RELAXED,
                                                          __HIP_MEMORY_SCOPE_AGENT);
                int n = 0;
                const int base = r << 6;
                while (mm) {
                    int bit = __builtin_ctzll(mm);
                    mm &= mm - 1;
                    fidx[base + n] = base + bit;   // global fired neuron j
                    ++n;
                }
                cnt[r] = n;
            }
        }
        __syncthreads();   // masks/fidx/cnt ready; also protects LDS reuse (see notes)

        // gather: each wave g takes columns n = g, g+8, ... within each word
        float acc = 0.0f;
        for (int w = 0; w < NBLK; ++w) {
            const int kw = cnt[w];
            const int fb = w << 6;
            for (int n = g; n < kw; n += 8) {
                const int j = fidx[fb + n];
                acc += ST[((size_t)j << 10) + colbase];
            }
        }
        psum[(g << 6) + r] = acc;
        __syncthreads();   // psum ready

        if (act) {
            float I = data[t] * Ui;
            #pragma unroll
            for (int gg = 0; gg < 8; ++gg) I += psum[(gg << 6) + r];
            v = v + 0.5f * (0.04f * v * v + 5.0f * v + 140.0f - u + I);
            u = u + ai * (bi * v - u);
            const bool nf = (v >= 30.0f);
            out_states[(size_t)t * NN + i] = nf ? 1.0f : 0.0f;
            out_fir[(size_t)t * NN + i]   = fired ? 1.0f : 0.0f;
        }
        // no trailing barrier needed: wave 0 only overwrites fidx/cnt after it
        // passes the psum barrier, which all gather waves have also passed.
    }

    if (act) { out_v[i] = v; out_u[i] = u; }
}

extern "C" void kernel_launch(void* const* d_in, const int* in_sizes, int n_in,
                              void* d_out, int out_size, void* d_ws, size_t ws_size,
                              hipStream_t stream) {
    const float* data = (const float*)d_in[0];
    const float* U    = (const float*)d_in[1];
    const float* S    = (const float*)d_in[2];
    const float* a    = (const float*)d_in[3];
    const float* b    = (const float*)d_in[4];
    const float* c    = (const float*)d_in[5];
    const float* dd   = (const float*)d_in[6];
    const float* v0   = (const float*)d_in[7];
    const float* u0   = (const float*)d_in[8];
    const int T = in_sizes[0];   // 16384

    float* ST  = (float*)d_ws;
    Comm* comm = (Comm*)((char*)d_ws + COMM_OFF);

    float* out        = (float*)d_out;
    float* out_states = out;                          // [T, NN]
    float* out_v      = out + (size_t)T * NN;         // [NN]
    float* out_u      = out_v + NN;                   // [NN]
    float* out_fir    = out_u + NN;                   // [T, NN]

    hipLaunchKernelGGL(transpose_S, dim3((NN * NP) / 256), dim3(256), 0, stream, S, ST);
    // zero the comm flags every call (d_ws keeps stale stamps across graph replays)
    hipMemsetAsync(comm, 0, 2 * NBLK * sizeof(Comm), stream);
    hipLaunchKernelGGL(izhikevich_sim, dim3(NBLK), dim3(TPB), 0, stream,
                       data, U, ST, comm, a, b, c, dd, v0, u0,
                       out_states, out_v, out_u, out_fir, T);
}

// Round 3
// 42400.015 us; speedup vs baseline: 1.2492x; 1.2492x over previous
//
#include <hip/hip_runtime.h>
#include <stdint.h>

#define NN 1000
#define NP 1024
#define NBLK 16            // cooperating blocks, 64 neurons each
#define RPB 64             // rows (neurons) per block
#define TPB 512            // 8 waves: wave 0 = state+decode, waves 0..7 = gather
#define ST_FLOATS (NN * NP)            // 1,024,000 floats
#define COMM_OFF  (ST_FLOATS * 4)      // comm area after ST in d_ws (8/128-aligned)

typedef unsigned long long u64;
typedef unsigned int u32;

// comm: u64 words[2][2*NBLK]; word = (stamp<<32) | mask_half, stamp = t+1.
// Self-validating 8B atomic units -> relaxed (fence-free) protocol is sound.

// S[NN][NN] row-major -> ST[j][i], column j contiguous over padded i (stride 1024).
__global__ void transpose_S(const float* __restrict__ S, float* __restrict__ ST) {
    int idx = blockIdx.x * blockDim.x + threadIdx.x;   // 0 .. NN*NP-1
    int j = idx >> 10;          // 0..999
    int i = idx & (NP - 1);     // 0..1023
    float val = (i < NN) ? S[i * NN + j] : 0.0f;
    ST[(j << 10) + i] = val;
}

__global__ void __launch_bounds__(TPB) izhikevich_sim(
    const float* __restrict__ data, const float* __restrict__ U,
    const float* __restrict__ ST, u64* __restrict__ comm,
    const float* __restrict__ a, const float* __restrict__ b,
    const float* __restrict__ c, const float* __restrict__ d,
    const float* __restrict__ v0, const float* __restrict__ u0,
    float* __restrict__ out_states, float* __restrict__ out_v,
    float* __restrict__ out_u, float* __restrict__ out_fir, int T)
{
    __shared__ int   cnt[NBLK];
    __shared__ int   fidx[NBLK * 64];
    __shared__ float psum[8 * RPB];
    __shared__ u32   mhalf[2 * NBLK];

    const int tid = threadIdx.x;
    const int g   = tid >> 6;            // wave id 0..7
    const int r   = tid & 63;            // lane
    const int blk = blockIdx.x;
    const int i   = blk * RPB + r;       // neuron owned by wave-0 lane r
    const bool isw0 = (g == 0);
    const bool act  = isw0 && (i < NN);

    float v = 0.f, u = 0.f, ai = 0.f, bi = 0.f, ci = 0.f, di = 0.f, Ui = 0.f;
    if (act) {
        v = v0[i]; u = u0[i];
        ai = a[i]; bi = b[i]; ci = c[i]; di = d[i]; Ui = U[i];
    }
    bool fired = false;
    const int colbase = (blk << 6) + r;  // row offset within a 1024-stride column

    for (int t = 0; t < T; ++t) {
        u64* words = comm + (size_t)(t & 1) * (2 * NBLK);
        if (isw0) {
            fired = act && (v >= 30.0f);
            u64 m = __ballot(fired);
            // publish: lanes 0,1 each store one self-stamped half (relaxed = no
            // waitcnt / no wbl2 / no inv on the critical path)
            if (r < 2) {
                u64 wv = ((u64)(u32)(t + 1) << 32) | (u64)(u32)(m >> (r * 32));
                __hip_atomic_store(&words[(blk << 1) + r], wv,
                                   __ATOMIC_RELAXED, __HIP_MEMORY_SCOPE_AGENT);
            }
            // reference applies reset twice: v=c (idempotent), u += 2*d
            if (fired) { v = ci; u += 2.0f * di; }

            // poll: 32 lanes, one coalesced relaxed atomic load per spin iter
            if (r < 2 * NBLK) {
                u64 wv;
                do {
                    wv = __hip_atomic_load(&words[r], __ATOMIC_RELAXED,
                                           __HIP_MEMORY_SCOPE_AGENT);
                } while ((int)(u32)(wv >> 32) < t + 1);
                mhalf[r] = (u32)wv;
            }
            // decode: lanes 0..15 expand masks to fired-index lists
            if (r < NBLK) {
                u64 mm = (u64)mhalf[2 * r] | ((u64)mhalf[2 * r + 1] << 32);
                int n = 0;
                const int base = r << 6;
                while (mm) {
                    int bit = __builtin_ctzll(mm);
                    mm &= mm - 1;
                    fidx[base + n] = base + bit;
                    ++n;
                }
                cnt[r] = n;
            }
        }
        __syncthreads();   // fidx/cnt ready

        // gather: wave g takes columns n = g, g+8, ... within each 64-neuron word
        float acc = 0.0f;
        for (int w = 0; w < NBLK; ++w) {
            const int kw = cnt[w];
            const int fb = w << 6;
            for (int n = g; n < kw; n += 8) {
                const int j = fidx[fb + n];
                acc += ST[((size_t)j << 10) + colbase];
            }
        }
        psum[(g << 6) + r] = acc;
        __syncthreads();   // psum ready

        if (act) {
            float I = data[t] * Ui;
            #pragma unroll
            for (int gg = 0; gg < 8; ++gg) I += psum[(gg << 6) + r];
            v = v + 0.5f * (0.04f * v * v + 5.0f * v + 140.0f - u + I);
            u = u + ai * (bi * v - u);
            const bool nf = (v >= 30.0f);
            out_states[(size_t)t * NN + i] = nf ? 1.0f : 0.0f;
            out_fir[(size_t)t * NN + i]   = fired ? 1.0f : 0.0f;
        }
        // wave 0 only rewrites fidx/cnt after the psum barrier of this step,
        // which every gather wave has also passed -> no trailing barrier.
    }

    if (act) { out_v[i] = v; out_u[i] = u; }
}

extern "C" void kernel_launch(void* const* d_in, const int* in_sizes, int n_in,
                              void* d_out, int out_size, void* d_ws, size_t ws_size,
                              hipStream_t stream) {
    const float* data = (const float*)d_in[0];
    const float* U    = (const float*)d_in[1];
    const float* S    = (const float*)d_in[2];
    const float* a    = (const float*)d_in[3];
    const float* b    = (const float*)d_in[4];
    const float* c    = (const float*)d_in[5];
    const float* dd   = (const float*)d_in[6];
    const float* v0   = (const float*)d_in[7];
    const float* u0   = (const float*)d_in[8];
    const int T = in_sizes[0];   // 16384

    float* ST  = (float*)d_ws;
    u64*  comm = (u64*)((char*)d_ws + COMM_OFF);

    float* out        = (float*)d_out;
    float* out_states = out;                          // [T, NN]
    float* out_v      = out + (size_t)T * NN;         // [NN]
    float* out_u      = out_v + NN;                   // [NN]
    float* out_fir    = out_u + NN;                   // [T, NN]

    hipLaunchKernelGGL(transpose_S, dim3((NN * NP) / 256), dim3(256), 0, stream, S, ST);
    // zero the stamp ring every call (graph replays must not see stale stamps)
    hipMemsetAsync(comm, 0, 2 * (2 * NBLK) * sizeof(u64), stream);
    hipLaunchKernelGGL(izhikevich_sim, dim3(NBLK), dim3(TPB), 0, stream,
                       data, U, ST, comm, a, b, c, dd, v0, u0,
                       out_states, out_v, out_u, out_fir, T);
}

// Round 4
// 28036.780 us; speedup vs baseline: 1.8892x; 1.5123x over previous
//
#include <hip/hip_runtime.h>
#include <stdint.h>

#define NN 1000
#define NP 1024
#define TPB 512          // 8 waves; thread tid owns rows 2*tid and 2*tid+1

typedef unsigned int u32;
typedef unsigned long long u64;

// S[NN][NN] row-major fp32 -> ST16[j][i] fp16: column j contiguous over padded
// row index i (stride 1024 halves = 2KB). Padding rows i>=NN are zero.
__global__ void transpose_S_f16(const float* __restrict__ S, _Float16* __restrict__ ST) {
    int idx = blockIdx.x * blockDim.x + threadIdx.x;   // 0 .. NN*NP-1
    int j = idx >> 10;          // source neuron / column 0..999
    int i = idx & (NP - 1);     // target row 0..1023
    float val = (i < NN) ? S[i * NN + j] : 0.0f;
    ST[(j << 10) + i] = (_Float16)val;   // RTE
}

__global__ void __launch_bounds__(TPB) izhikevich_sim(
    const float* __restrict__ data, const float* __restrict__ U,
    const _Float16* __restrict__ ST,
    const float* __restrict__ a, const float* __restrict__ b,
    const float* __restrict__ c, const float* __restrict__ d,
    const float* __restrict__ v0, const float* __restrict__ u0,
    float* __restrict__ out_states, float* __restrict__ out_v,
    float* __restrict__ out_u, float* __restrict__ out_fir, int T)
{
    __shared__ u64 wm0[8];        // fired mask, even rows of wave w's 128-row span
    __shared__ u64 wm1[8];        // odd rows
    __shared__ int cnt[8];        // fired count per 128-row span
    __shared__ int fidx[8 * 128]; // fired row indices per span

    const int tid  = threadIdx.x;
    const int w    = tid >> 6;
    const int lane = tid & 63;
    const int r0   = tid << 1;          // even row
    const bool act = (r0 < NN);         // covers r0,r0+1 (r0<=998 -> r1<=999)

    float v0r = 0.f, v1r = 0.f, u0r = 0.f, u1r = 0.f;
    float a0 = 0.f, a1 = 0.f, b0 = 0.f, b1 = 0.f, c0 = 0.f, c1 = 0.f;
    float d0 = 0.f, d1 = 0.f, U0 = 0.f, U1 = 0.f;
    if (act) {
        float2 t2;
        t2 = *(const float2*)&v0[r0]; v0r = t2.x; v1r = t2.y;
        t2 = *(const float2*)&u0[r0]; u0r = t2.x; u1r = t2.y;
        t2 = *(const float2*)&a[r0];  a0 = t2.x;  a1 = t2.y;
        t2 = *(const float2*)&b[r0];  b0 = t2.x;  b1 = t2.y;
        t2 = *(const float2*)&c[r0];  c0 = t2.x;  c1 = t2.y;
        t2 = *(const float2*)&d[r0];  d0 = t2.x;  d1 = t2.y;
        t2 = *(const float2*)&U[r0];  U0 = t2.x;  U1 = t2.y;
    }

    const u32* __restrict__ STu = (const u32*)ST;   // u32 tid of column j = rows 2tid,2tid+1

    for (int t = 0; t < T; ++t) {
        // --- fired masks at start of step t ---
        const bool f0 = act && (v0r >= 30.0f);
        const bool f1 = act && (v1r >= 30.0f);
        const u64 bal0 = __ballot(f0);
        const u64 bal1 = __ballot(f1);
        if (lane == 0) { wm0[w] = bal0; wm1[w] = bal1; }
        // reference applies reset twice: v=c (idempotent), u += 2*d
        if (f0) { v0r = c0; u0r += 2.0f * d0; }
        if (f1) { v1r = c1; u1r += 2.0f * d1; }
        __syncthreads();                         // barrier 1: masks ready

        // --- decode: 8 lanes of wave 0 expand their 128-row span ---
        if (w == 0 && lane < 8) {
            u64 m0 = wm0[lane], m1 = wm1[lane];
            const int base = lane << 7;          // fidx chunk base & row base
            int n = 0;
            while (m0) {
                int bit = __builtin_ctzll(m0); m0 &= m0 - 1;
                fidx[base + n] = base + (bit << 1); ++n;
            }
            while (m1) {
                int bit = __builtin_ctzll(m1); m1 &= m1 - 1;
                fidx[base + n] = base + (bit << 1) + 1; ++n;
            }
            cnt[lane] = n;
        }
        __syncthreads();                         // barrier 2: fidx/cnt ready

        // --- gather: every thread accumulates its 2 rows over all fired cols ---
        const float xt = data[t];
        float I0 = xt * U0, I1 = xt * U1;
        for (int ww = 0; ww < 8; ++ww) {
            const int kw = cnt[ww];
            const int fb = ww << 7;
            int n = 0;
            for (; n + 3 < kw; n += 4) {
                const int j0 = fidx[fb + n + 0] << 9;
                const int j1 = fidx[fb + n + 1] << 9;
                const int j2 = fidx[fb + n + 2] << 9;
                const int j3 = fidx[fb + n + 3] << 9;
                const u32 p0 = STu[j0 + tid];
                const u32 p1 = STu[j1 + tid];
                const u32 p2 = STu[j2 + tid];
                const u32 p3 = STu[j3 + tid];
                union { u32 u; _Float16 h[2]; } cv;
                cv.u = p0; I0 += (float)cv.h[0]; I1 += (float)cv.h[1];
                cv.u = p1; I0 += (float)cv.h[0]; I1 += (float)cv.h[1];
                cv.u = p2; I0 += (float)cv.h[0]; I1 += (float)cv.h[1];
                cv.u = p3; I0 += (float)cv.h[0]; I1 += (float)cv.h[1];
            }
            for (; n < kw; ++n) {
                const u32 p = STu[(fidx[fb + n] << 9) + tid];
                union { u32 u; _Float16 h[2]; } cv;
                cv.u = p; I0 += (float)cv.h[0]; I1 += (float)cv.h[1];
            }
        }

        // --- update + outputs ---
        if (act) {
            v0r = v0r + 0.5f * (0.04f * v0r * v0r + 5.0f * v0r + 140.0f - u0r + I0);
            u0r = u0r + a0 * (b0 * v0r - u0r);
            v1r = v1r + 0.5f * (0.04f * v1r * v1r + 5.0f * v1r + 140.0f - u1r + I1);
            u1r = u1r + a1 * (b1 * v1r - u1r);
            float2 st, fr;
            st.x = (v0r >= 30.0f) ? 1.0f : 0.0f;
            st.y = (v1r >= 30.0f) ? 1.0f : 0.0f;
            fr.x = f0 ? 1.0f : 0.0f;
            fr.y = f1 ? 1.0f : 0.0f;
            *(float2*)&out_states[(size_t)t * NN + r0] = st;
            *(float2*)&out_fir[(size_t)t * NN + r0]   = fr;
        }
        // no third barrier: any wave entering step t+1's mask-write has passed
        // barrier 2 of step t (so decode(t) is done), and decode(t+1) happens
        // after barrier 1 of step t+1 (so all gathers of step t are done).
    }

    if (act) {
        float2 vv, uu;
        vv.x = v0r; vv.y = v1r;
        uu.x = u0r; uu.y = u1r;
        *(float2*)&out_v[r0] = vv;
        *(float2*)&out_u[r0] = uu;
    }
}

extern "C" void kernel_launch(void* const* d_in, const int* in_sizes, int n_in,
                              void* d_out, int out_size, void* d_ws, size_t ws_size,
                              hipStream_t stream) {
    const float* data = (const float*)d_in[0];
    const float* U    = (const float*)d_in[1];
    const float* S    = (const float*)d_in[2];
    const float* a    = (const float*)d_in[3];
    const float* b    = (const float*)d_in[4];
    const float* c    = (const float*)d_in[5];
    const float* dd   = (const float*)d_in[6];
    const float* v0   = (const float*)d_in[7];
    const float* u0   = (const float*)d_in[8];
    const int T = in_sizes[0];   // 16384

    _Float16* ST = (_Float16*)d_ws;   // NN*NP halves = 2 MB

    float* out        = (float*)d_out;
    float* out_states = out;                          // [T, NN]
    float* out_v      = out + (size_t)T * NN;         // [NN]
    float* out_u      = out_v + NN;                   // [NN]
    float* out_fir    = out_u + NN;                   // [T, NN]

    hipLaunchKernelGGL(transpose_S_f16, dim3((NN * NP) / 256), dim3(256), 0, stream, S, ST);
    hipLaunchKernelGGL(izhikevich_sim, dim3(1), dim3(TPB), 0, stream,
                       data, U, ST, a, b, c, dd, v0, u0,
                       out_states, out_v, out_u, out_fir, T);
}

// Round 5
// 19862.115 us; speedup vs baseline: 2.6667x; 1.4116x over previous
//
#include <hip/hip_runtime.h>
#include <stdint.h>

#define NN 1000
#define NP 1024
#define TPB 512          // 8 waves; thread tid owns rows 2*tid and 2*tid+1
#define TT 16384         // LDS-staged input length

typedef unsigned int u32;
typedef unsigned long long u64;
typedef _Float16 half2v __attribute__((ext_vector_type(2)));

// S[NN][NN] row-major fp32 -> ST16[j][i] fp16, column j contiguous over padded
// row i (stride 1024 halves = 2KB). ALL NP columns written; cols >= NN are zero
// so they can serve as no-op padding targets for the unrolled gather.
__global__ void transpose_S_f16(const float* __restrict__ S, _Float16* __restrict__ ST) {
    int idx = blockIdx.x * blockDim.x + threadIdx.x;   // 0 .. NP*NP-1
    int j = idx >> 10;          // column 0..1023
    int i = idx & (NP - 1);     // row 0..1023
    float val = (i < NN && j < NN) ? S[i * NN + j] : 0.0f;
    ST[(j << 10) + i] = (_Float16)val;   // RTE
}

__device__ __forceinline__ void acc_pair(u32 p, float& A0, float& A1) {
#if __has_builtin(__builtin_amdgcn_fdot2)
    union { u32 u; half2v h; } cv; cv.u = p;
    const half2v E0 = {(_Float16)1.0f, (_Float16)0.0f};
    const half2v E1 = {(_Float16)0.0f, (_Float16)1.0f};
    A0 = __builtin_amdgcn_fdot2(cv.h, E0, A0, false);
    A1 = __builtin_amdgcn_fdot2(cv.h, E1, A1, false);
#else
    union { u32 u; _Float16 h[2]; } cv; cv.u = p;
    A0 += (float)cv.h[0];
    A1 += (float)cv.h[1];
#endif
}

__global__ void __launch_bounds__(TPB) izhikevich_sim(
    const float* __restrict__ data, const float* __restrict__ U,
    const _Float16* __restrict__ ST,
    const float* __restrict__ a, const float* __restrict__ b,
    const float* __restrict__ c, const float* __restrict__ d,
    const float* __restrict__ v0, const float* __restrict__ u0,
    float* __restrict__ out_states, float* __restrict__ out_v,
    float* __restrict__ out_u, float* __restrict__ out_fir, int T)
{
    __shared__ float sdata[TT];        // input currents staged once
    __shared__ u64 wm0[8];             // fired mask, even rows of wave w's span
    __shared__ u64 wm1[8];             // odd rows
    __shared__ int fidx[NP + 8];       // flat fired-column list + unroll pad
    __shared__ int sKtot;

    const int tid  = threadIdx.x;
    const int w    = tid >> 6;
    const int lane = tid & 63;
    const int r0   = tid << 1;
    const bool act = (r0 < NN);

    // stage data[] into LDS (vectorized, one time)
    {
        const int nv = T >> 2;
        const float4* d4 = (const float4*)data;
        float4* s4 = (float4*)sdata;
        for (int n = tid; n < nv && (n << 2) < TT; n += TPB) s4[n] = d4[n];
        for (int n = (nv << 2) + tid; n < T && n < TT; n += TPB) sdata[n] = data[n];
    }

    float v0r = 0.f, v1r = 0.f, u0r = 0.f, u1r = 0.f;
    float a0 = 0.f, a1 = 0.f, b0 = 0.f, b1 = 0.f, c0 = 0.f, c1 = 0.f;
    float d0 = 0.f, d1 = 0.f, U0 = 0.f, U1 = 0.f;
    if (act) {
        float2 t2;
        t2 = *(const float2*)&v0[r0]; v0r = t2.x; v1r = t2.y;
        t2 = *(const float2*)&u0[r0]; u0r = t2.x; u1r = t2.y;
        t2 = *(const float2*)&a[r0];  a0 = t2.x;  a1 = t2.y;
        t2 = *(const float2*)&b[r0];  b0 = t2.x;  b1 = t2.y;
        t2 = *(const float2*)&c[r0];  c0 = t2.x;  c1 = t2.y;
        t2 = *(const float2*)&d[r0];  d0 = t2.x;  d1 = t2.y;
        t2 = *(const float2*)&U[r0];  U0 = t2.x;  U1 = t2.y;
    }
    __syncthreads();   // sdata ready

    const u32* __restrict__ STu = (const u32*)ST;  // u32 tid of column j = rows 2tid,2tid+1

    for (int t = 0; t < T; ++t) {
        // --- fired masks at start of step t ---
        const bool f0 = act && (v0r >= 30.0f);
        const bool f1 = act && (v1r >= 30.0f);
        const u64 bal0 = __ballot(f0);
        const u64 bal1 = __ballot(f1);
        if (lane == 0) { wm0[w] = bal0; wm1[w] = bal1; }
        // reference applies reset twice: v=c (idempotent), u += 2*d
        if (f0) { v0r = c0; u0r += 2.0f * d0; }
        if (f1) { v1r = c1; u1r += 2.0f * d1; }
        __syncthreads();                          // barrier 1: masks ready

        // --- decode: 16 lanes of wave 0, one u64 each, flat compaction ---
        if (w == 0 && lane < 16) {
            u64 m = (lane < 8) ? wm0[lane] : wm1[lane - 8];
            const int pc = __popcll(m);
            int incl = pc;
            #pragma unroll
            for (int off = 1; off < 16; off <<= 1) {
                int o = __shfl_up(incl, off);
                if (lane >= off) incl += o;
            }
            int base = incl - pc;
            if (lane == 15) {
                sKtot = incl;
                #pragma unroll
                for (int p = 0; p < 8; ++p) fidx[incl + p] = NN;  // zero column
            }
            const int rowbase = (lane & 7) << 7;
            const int odd = lane >> 3;
            while (m) {
                int bit = __builtin_ctzll(m); m &= m - 1;
                fidx[base++] = rowbase + (bit << 1) + odd;
            }
        }
        __syncthreads();                          // barrier 2: fidx/sKtot ready

        // --- gather: unroll 8, two accumulator pairs for load parallelism ---
        const float xt = (t < TT) ? sdata[t] : data[t];
        float I0 = xt * U0, I1 = xt * U1;
        float J0 = 0.0f, J1 = 0.0f;
        const int ktot = sKtot;
        for (int n = 0; n < ktot; n += 8) {
            const int j0 = fidx[n + 0] << 9;
            const int j1 = fidx[n + 1] << 9;
            const int j2 = fidx[n + 2] << 9;
            const int j3 = fidx[n + 3] << 9;
            const int j4 = fidx[n + 4] << 9;
            const int j5 = fidx[n + 5] << 9;
            const int j6 = fidx[n + 6] << 9;
            const int j7 = fidx[n + 7] << 9;
            const u32 p0 = STu[j0 + tid];
            const u32 p1 = STu[j1 + tid];
            const u32 p2 = STu[j2 + tid];
            const u32 p3 = STu[j3 + tid];
            const u32 p4 = STu[j4 + tid];
            const u32 p5 = STu[j5 + tid];
            const u32 p6 = STu[j6 + tid];
            const u32 p7 = STu[j7 + tid];
            acc_pair(p0, I0, I1); acc_pair(p1, J0, J1);
            acc_pair(p2, I0, I1); acc_pair(p3, J0, J1);
            acc_pair(p4, I0, I1); acc_pair(p5, J0, J1);
            acc_pair(p6, I0, I1); acc_pair(p7, J0, J1);
        }
        I0 += J0; I1 += J1;

        // --- update + outputs ---
        if (act) {
            v0r = v0r + 0.5f * (0.04f * v0r * v0r + 5.0f * v0r + 140.0f - u0r + I0);
            u0r = u0r + a0 * (b0 * v0r - u0r);
            v1r = v1r + 0.5f * (0.04f * v1r * v1r + 5.0f * v1r + 140.0f - u1r + I1);
            u1r = u1r + a1 * (b1 * v1r - u1r);
            union { float2 f; u64 u; } st, fr;
            st.f.x = (v0r >= 30.0f) ? 1.0f : 0.0f;
            st.f.y = (v1r >= 30.0f) ? 1.0f : 0.0f;
            fr.f.x = f0 ? 1.0f : 0.0f;
            fr.f.y = f1 ? 1.0f : 0.0f;
            __builtin_nontemporal_store(st.u, (u64*)&out_states[(size_t)t * NN + r0]);
            __builtin_nontemporal_store(fr.u, (u64*)&out_fir[(size_t)t * NN + r0]);
        }
        // no third barrier: wave entering step t+1's mask-write passed barrier 2
        // of step t (decode(t) done); decode(t+1) happens after barrier 1 of
        // step t+1, by which point all gathers of step t (pre-barrier-1 work)
        // are complete.
    }

    if (act) {
        float2 vv, uu;
        vv.x = v0r; vv.y = v1r;
        uu.x = u0r; uu.y = u1r;
        *(float2*)&out_v[r0] = vv;
        *(float2*)&out_u[r0] = uu;
    }
}

extern "C" void kernel_launch(void* const* d_in, const int* in_sizes, int n_in,
                              void* d_out, int out_size, void* d_ws, size_t ws_size,
                              hipStream_t stream) {
    const float* data = (const float*)d_in[0];
    const float* U    = (const float*)d_in[1];
    const float* S    = (const float*)d_in[2];
    const float* a    = (const float*)d_in[3];
    const float* b    = (const float*)d_in[4];
    const float* c    = (const float*)d_in[5];
    const float* dd   = (const float*)d_in[6];
    const float* v0   = (const float*)d_in[7];
    const float* u0   = (const float*)d_in[8];
    const int T = in_sizes[0];   // 16384

    _Float16* ST = (_Float16*)d_ws;   // NP*NP halves = 2 MB

    float* out        = (float*)d_out;
    float* out_states = out;                          // [T, NN]
    float* out_v      = out + (size_t)T * NN;         // [NN]
    float* out_u      = out_v + NN;                   // [NN]
    float* out_fir    = out_u + NN;                   // [T, NN]

    hipLaunchKernelGGL(transpose_S_f16, dim3((NP * NP) / 256), dim3(256), 0, stream, S, ST);
    hipLaunchKernelGGL(izhikevich_sim, dim3(1), dim3(TPB), 0, stream,
                       data, U, ST, a, b, c, dd, v0, u0,
                       out_states, out_v, out_u, out_fir, T);
}